// Round 1
// 2341.544 us; speedup vs baseline: 3.5624x; 3.5624x over previous
//
#include <hip/hip_runtime.h>
#include <hip/hip_bf16.h>
#include <math.h>
#include <stdint.h>

// SimpleSSMLayer on gfx950 — Round 10: DE-CHUNK THE GEMMs.
// R9 counters: k2 @ 64 blocks/dispatch, Occupancy 2.7%, VALUBusy 7.6%,
// HBM 0.9% — parallelism-starved, not compute/memory-bound. Only the scan
// is sequential in time; k1/k2 are not. This round:
//   * k1 runs ONCE over all B*T=8192 rows (grid 64x128 = 8192 blocks).
//   * kscan runs ONCE, grid (DI/16, B) = 512 blocks; h carried in registers
//     across the whole T=2048 (no hstate buffer, no kzero/ktail kernels;
//     conv history rows read directly from full XIN, zero-filled at t<0).
//   * k2 runs ONCE (grid 16x128 = 2048 blocks) with kpre fused into its
//     epilogue: out = acc + bo + meanDv*x  (pure store, no RMW pass).
//   * G is written IN-PLACE over silu(z) (same element), saving 33.5 MB ws.
// GEMM inner bodies are identical to the R9-verified ones; staging loads
// explicitly vectorized (float4 / uint4 bf16-unpack).
// ws layout (bytes):
//   [0)         meanDv (float)                      pad to 256
//   [256)       XIN: Mrows*DI bf16  = 33,554,432
//   [33554688)  ZG : Mrows*DI bf16  = 33,554,432    (silu(z), then G in-place)
//   total 67,109,120 B

using bf16 = __hip_bfloat16;

static constexpr int Bdim = 4;
static constexpr int Tdim = 2048;
static constexpr int DM   = 1024;
static constexpr int DI   = 2048;
static constexpr int DS   = 16;
static constexpr int DC   = 4;
static constexpr int DTR  = 32;
static constexpr int Mrows = Bdim * Tdim;   // 8192

__device__ __forceinline__ float b2f(bf16 v) { return __bfloat162float(v); }
__device__ __forceinline__ bf16  f2b(float v) { return __float2bfloat16(v); }
__device__ __forceinline__ float silu_f(float v) { return v / (1.0f + __expf(-v)); }
__device__ __forceinline__ float softplus_f(float v) {
  return (v > 15.0f) ? v : log1pf(__expf(v));
}

// --------------------------------------------------------------------------
__global__ __launch_bounds__(256)
void kmean(const float* __restrict__ Dv, float* __restrict__ meanp) {
  __shared__ float red[256];
  float s = 0.0f;
  for (int i = threadIdx.x; i < DI; i += 256) s += Dv[i];
  red[threadIdx.x] = s;
  __syncthreads();
  for (int o = 128; o > 0; o >>= 1) {
    if (threadIdx.x < o) red[threadIdx.x] += red[threadIdx.x + o];
    __syncthreads();
  }
  if (threadIdx.x == 0) *meanp = red[0] / (float)DI;
}

// --------------------------------------------------------------------------
// k1: full GEMM  xz = x @ Wi^T + bi over all Mrows rows.
// x_in -> XIN[row][0..DI), silu(z) -> ZG[row][0..DI).  Grid (2*DI/64, Mrows/64).
// --------------------------------------------------------------------------
__global__ __launch_bounds__(256)
void k1(const float* __restrict__ A, const float* __restrict__ W,
        const float* __restrict__ bi,
        bf16* __restrict__ XIN, bf16* __restrict__ ZG)
{
  __shared__ float As[64][36];
  __shared__ float Bs[64][36];
  const int tid = threadIdx.x;
  const int bm = blockIdx.y * 64;
  const int bn = blockIdx.x * 64;
  const int tr = tid >> 4, tc = tid & 15;
  const int lr = tid >> 2, lc = (tid & 3) * 8;
  const int K = DM;

  float acc[4][4] = {};
  for (int k0 = 0; k0 < K; k0 += 32) {
    __syncthreads();
    {
      const float* ga = A + (size_t)(bm + lr) * K + k0 + lc;
      const float* gb = W + (size_t)(bn + lr) * K + k0 + lc;
      const float4 a0 = *reinterpret_cast<const float4*>(ga);
      const float4 a1 = *reinterpret_cast<const float4*>(ga + 4);
      const float4 b0 = *reinterpret_cast<const float4*>(gb);
      const float4 b1 = *reinterpret_cast<const float4*>(gb + 4);
      As[lr][lc + 0] = a0.x; As[lr][lc + 1] = a0.y;
      As[lr][lc + 2] = a0.z; As[lr][lc + 3] = a0.w;
      As[lr][lc + 4] = a1.x; As[lr][lc + 5] = a1.y;
      As[lr][lc + 6] = a1.z; As[lr][lc + 7] = a1.w;
      Bs[lr][lc + 0] = b0.x; Bs[lr][lc + 1] = b0.y;
      Bs[lr][lc + 2] = b0.z; Bs[lr][lc + 3] = b0.w;
      Bs[lr][lc + 4] = b1.x; Bs[lr][lc + 5] = b1.y;
      Bs[lr][lc + 6] = b1.z; Bs[lr][lc + 7] = b1.w;
    }
    __syncthreads();
#pragma unroll
    for (int k2 = 0; k2 < 32; ++k2) {
      float al[4], bl[4];
#pragma unroll
      for (int i = 0; i < 4; ++i) { al[i] = As[tr + 16 * i][k2]; bl[i] = Bs[tc + 16 * i][k2]; }
#pragma unroll
      for (int i = 0; i < 4; ++i)
#pragma unroll
        for (int j = 0; j < 4; ++j) acc[i][j] += al[i] * bl[j];
    }
  }
#pragma unroll
  for (int i = 0; i < 4; ++i) {
    const int m = bm + tr + 16 * i;                 // global row
#pragma unroll
    for (int j = 0; j < 4; ++j) {
      const int nn = bn + tc + 16 * j;
      const float v = acc[i][j] + bi[nn];
      if (nn < DI) XIN[(size_t)m * DI + nn] = f2b(v);
      else         ZG [(size_t)m * DI + (nn - DI)] = f2b(silu_f(v));
    }
  }
}

// --------------------------------------------------------------------------
// kscan: fused conv+dt+scan+gate over FULL T per (batch, d-block).
// Grid (DI/16, Bdim), 256 thr = 16d x 16n. h carried in registers for all T.
// Conv history (t<0) is zero; otherwise read directly from XIN (same batch).
// Gate applied in-place: ZG[gi] = y * silu(z)[gi].
// --------------------------------------------------------------------------
__global__ __launch_bounds__(256)
void kscan(const bf16* __restrict__ XIN, bf16* __restrict__ ZG,
           const float* __restrict__ cw, const float* __restrict__ cb,
           const float* __restrict__ Wdt, const float* __restrict__ bdt,
           const float* __restrict__ A_log, const float* __restrict__ Bm,
           const float* __restrict__ Cm)
{
  __shared__ float Wl[16][33];
  __shared__ float x32[64][33];
  __shared__ float xc[67][17];
  __shared__ float dts[64 * 16];
  __shared__ float us [64 * 16];
  __shared__ float ys [64 * 16];

  const int tid = threadIdx.x;
  const int n  = tid & 15;
  const int dl = tid >> 4;
  const int d0 = blockIdx.x * 16;
  const int d  = d0 + dl;
  const size_t rbase = (size_t)blockIdx.y * Tdim;   // first row of this batch

  const float Af = -__expf(A_log[(size_t)d * DS + n]);
  const float Bf = Bm[(size_t)d * DS + n];
  const float Cf = Cm[(size_t)d * DS + n];
  const float w0 = cw[d * DC + 0], w1 = cw[d * DC + 1];
  const float w2 = cw[d * DC + 2], w3 = cw[d * DC + 3];
  const float c0 = cb[d];
  const float bdtv = bdt[d];

  for (int e = tid; e < 16 * DTR; e += 256)
    Wl[e >> 5][e & 31] = Wdt[(size_t)(d0 + (e >> 5)) * DTR + (e & 31)];

  float h = 0.0f;

  for (int t0 = 0; t0 < Tdim; t0 += 64) {
    __syncthreads();
    for (int e = tid; e < 64 * 32; e += 256) {
      const int tl = e >> 5, r = e & 31;
      x32[tl][r] = b2f(XIN[(rbase + t0 + tl) * DI + r]);
    }
    for (int e = tid; e < 67 * 16; e += 256) {
      const int i = e >> 4, dd = e & 15;
      const int rr = t0 + i - 3;                    // time index of this row
      xc[i][dd] = (rr < 0) ? 0.0f
                           : b2f(XIN[(rbase + rr) * DI + d0 + dd]);
    }
    __syncthreads();

#pragma unroll
    for (int q = 0; q < 4; ++q) {
      const int tl = n + 16 * q;
      const float cv = c0 + w0 * xc[tl][dl] + w1 * xc[tl + 1][dl]
                          + w2 * xc[tl + 2][dl] + w3 * xc[tl + 3][dl];
      us[tl * 16 + dl] = silu_f(cv);
      float a = bdtv;
#pragma unroll
      for (int r = 0; r < DTR; ++r) a += x32[tl][r] * Wl[dl][r];
      dts[tl * 16 + dl] = softplus_f(a);
    }
    __syncthreads();

    for (int tl = 0; tl < 64; ++tl) {
      const float dtv = dts[tl * 16 + dl];
      const float uv  = us [tl * 16 + dl];
      h = h * __expf(dtv * Af) + (dtv * Bf) * uv;
      float y = h * Cf;
      y += __shfl_xor(y, 1);
      y += __shfl_xor(y, 2);
      y += __shfl_xor(y, 4);
      y += __shfl_xor(y, 8);
      if (n == 0) ys[tl * 16 + dl] = y;
    }
    __syncthreads();

    for (int e = tid; e < 64 * 16; e += 256) {
      const int tl = e >> 4, dd = e & 15;
      const size_t gi = (rbase + t0 + tl) * DI + d0 + dd;
      ZG[gi] = f2b(ys[e] * b2f(ZG[gi]));          // in-place gate: G = y*silu(z)
    }
  }
}

// --------------------------------------------------------------------------
// k2: full GEMM  out = G @ Wo^T + bo + meanDv*x  (kpre fused; pure store).
// Grid (DM/64, Mrows/64).
// --------------------------------------------------------------------------
__global__ __launch_bounds__(256)
void k2(const bf16* __restrict__ G, const float* __restrict__ Wo,
        const float* __restrict__ x, const float* __restrict__ bo,
        const float* __restrict__ meanp, float* __restrict__ out)
{
  __shared__ float As[64][36];
  __shared__ float Bs[64][36];
  const int tid = threadIdx.x;
  const int bm = blockIdx.y * 64;
  const int bn = blockIdx.x * 64;
  const int tr = tid >> 4, tc = tid & 15;
  const int lr = tid >> 2, lc = (tid & 3) * 8;
  const int K = DI;

  const float mv = *meanp;

  float acc[4][4] = {};
  for (int k0 = 0; k0 < K; k0 += 32) {
    __syncthreads();
    {
      const bf16*  ga = G  + (size_t)(bm + lr) * K + k0 + lc;
      const float* gb = Wo + (size_t)(bn + lr) * K + k0 + lc;
      const uint4 av = *reinterpret_cast<const uint4*>(ga);   // 8 bf16 = 16 B
      const uint32_t aw[4] = {av.x, av.y, av.z, av.w};
#pragma unroll
      for (int kk = 0; kk < 4; ++kk) {
        As[lr][lc + 2 * kk + 0] = __uint_as_float(aw[kk] << 16);
        As[lr][lc + 2 * kk + 1] = __uint_as_float(aw[kk] & 0xffff0000u);
      }
      const float4 b0 = *reinterpret_cast<const float4*>(gb);
      const float4 b1 = *reinterpret_cast<const float4*>(gb + 4);
      Bs[lr][lc + 0] = b0.x; Bs[lr][lc + 1] = b0.y;
      Bs[lr][lc + 2] = b0.z; Bs[lr][lc + 3] = b0.w;
      Bs[lr][lc + 4] = b1.x; Bs[lr][lc + 5] = b1.y;
      Bs[lr][lc + 6] = b1.z; Bs[lr][lc + 7] = b1.w;
    }
    __syncthreads();
#pragma unroll
    for (int k2i = 0; k2i < 32; ++k2i) {
      float al[4], bl[4];
#pragma unroll
      for (int i = 0; i < 4; ++i) { al[i] = As[tr + 16 * i][k2i]; bl[i] = Bs[tc + 16 * i][k2i]; }
#pragma unroll
      for (int i = 0; i < 4; ++i)
#pragma unroll
        for (int j = 0; j < 4; ++j) acc[i][j] += al[i] * bl[j];
    }
  }
#pragma unroll
  for (int i = 0; i < 4; ++i) {
    const int m = bm + tr + 16 * i;
#pragma unroll
    for (int j = 0; j < 4; ++j) {
      const int nn = bn + tc + 16 * j;
      const size_t oi = (size_t)m * DM + nn;
      out[oi] = acc[i][j] + bo[nn] + mv * x[oi];
    }
  }
}

// --------------------------------------------------------------------------
extern "C" void kernel_launch(void* const* d_in, const int* in_sizes, int n_in,
                              void* d_out, int out_size, void* d_ws, size_t ws_size,
                              hipStream_t stream)
{
  const float* x    = (const float*)d_in[0];
  const float* Wi   = (const float*)d_in[1];
  const float* bi   = (const float*)d_in[2];
  const float* cw   = (const float*)d_in[3];
  const float* cb   = (const float*)d_in[4];
  const float* Wdt  = (const float*)d_in[5];
  const float* bdt  = (const float*)d_in[6];
  const float* Alog = (const float*)d_in[7];
  const float* Bm   = (const float*)d_in[8];
  const float* Cm   = (const float*)d_in[9];
  const float* Dv   = (const float*)d_in[10];
  const float* Wo   = (const float*)d_in[11];
  const float* bo   = (const float*)d_in[12];
  float* out = (float*)d_out;

  char* ws = (char*)d_ws;
  float* MEANP = (float*)(ws);
  bf16*  XIN   = (bf16*)(ws + 256);
  bf16*  ZG    = (bf16*)(ws + 256 + (size_t)Mrows * DI * sizeof(bf16));
  // total ws use: 256 + 2*33,554,432 = 67,109,120 B

  kmean<<<1, 256, 0, stream>>>(Dv, MEANP);
  k1<<<dim3(2 * DI / 64, Mrows / 64), 256, 0, stream>>>(x, Wi, bi, XIN, ZG);
  kscan<<<dim3(DI / 16, Bdim), 256, 0, stream>>>(
      XIN, ZG, cw, cb, Wdt, bdt, Alog, Bm, Cm);
  k2<<<dim3(DM / 64, Mrows / 64), 256, 0, stream>>>(ZG, Wo, x, bo, MEANP, out);
}

// Round 2
// 664.144 us; speedup vs baseline: 12.5597x; 3.5257x over previous
//
#include <hip/hip_runtime.h>
#include <hip/hip_bf16.h>
#include <math.h>
#include <stdint.h>

// SimpleSSMLayer on gfx950 — Round 11: MFMA GEMMs + latency-fixed scan.
// R10 counters: k1 MfmaUtil=0, VALUBusy=64%, 54.6 TF fp32-VALU — wrong pipe.
// This round:
//   * kcvt: x/Wi/Wo -> bf16 once in ws (~25 us BW-bound).
//   * k1,k2: v_mfma_f32_16x16x32_bf16, 128x128 tile, BK=32, 4 waves x 4x4
//     frags, global_load_lds(16B) linear-LDS staging, 2-barrier K-loop
//     (m97 structure). fp32 accumulate; epilogues unchanged numerically
//     except bf16-rounded GEMM inputs.
//   * kscan: dt/u stored transposed+padded [16][68]; serial loop reads one
//     float4 per 4 steps (was 2 scalar ds_read per step); y-reduction via
//     pure-VALU DPP row_shr tree (was 4 ds-pipe shfl_xor per step).
// ws layout (bytes):
//   [0)        meanDv                         pad 256
//   [256)      XB : 8192x1024 bf16 = 16,777,216
//   [16777472) WIB: 4096x1024 bf16 =  8,388,608
//   [25166080) WOB: 1024x2048 bf16 =  4,194,304
//   [29360384) XIN: 8192x2048 bf16 = 33,554,432
//   [62914816) ZG : 8192x2048 bf16 = 33,554,432   total 96,469,248 B

using bf16 = __hip_bfloat16;
typedef __attribute__((ext_vector_type(8))) __bf16 bf16x8;
typedef __attribute__((ext_vector_type(4))) float f32x4;

static constexpr int Bdim = 4;
static constexpr int Tdim = 2048;
static constexpr int DM   = 1024;
static constexpr int DI   = 2048;
static constexpr int DS   = 16;
static constexpr int DC   = 4;
static constexpr int DTR  = 32;
static constexpr int Mrows = Bdim * Tdim;   // 8192

__device__ __forceinline__ float b2f(bf16 v) { return __bfloat162float(v); }
__device__ __forceinline__ bf16  f2b(float v) { return __float2bfloat16(v); }
__device__ __forceinline__ float silu_f(float v) { return v / (1.0f + __expf(-v)); }
__device__ __forceinline__ float softplus_f(float v) {
  return (v > 15.0f) ? v : log1pf(__expf(v));
}

#define GLOAD_LDS16(gp, lp)                                                  \
  __builtin_amdgcn_global_load_lds(                                          \
      (const __attribute__((address_space(1))) uint32_t*)(gp),               \
      (__attribute__((address_space(3))) uint32_t*)(lp), 16, 0, 0)

// --------------------------------------------------------------------------
__global__ __launch_bounds__(256)
void kmean(const float* __restrict__ Dv, float* __restrict__ meanp) {
  __shared__ float red[256];
  float s = 0.0f;
  for (int i = threadIdx.x; i < DI; i += 256) s += Dv[i];
  red[threadIdx.x] = s;
  __syncthreads();
  for (int o = 128; o > 0; o >>= 1) {
    if (threadIdx.x < o) red[threadIdx.x] += red[threadIdx.x + o];
    __syncthreads();
  }
  if (threadIdx.x == 0) *meanp = red[0] / (float)DI;
}

// fp32 -> bf16 bulk convert, 8 elems/thread
__device__ __forceinline__ unsigned pack2(float x, float y) {
  return (unsigned)__builtin_bit_cast(unsigned short, f2b(x)) |
         ((unsigned)__builtin_bit_cast(unsigned short, f2b(y)) << 16);
}
__global__ __launch_bounds__(256)
void kcvt(const float* __restrict__ src, bf16* __restrict__ dst, int n8) {
  const int i = blockIdx.x * 256 + threadIdx.x;
  if (i >= n8) return;
  const float4 a = reinterpret_cast<const float4*>(src)[2 * i];
  const float4 b = reinterpret_cast<const float4*>(src)[2 * i + 1];
  uint4 v;
  v.x = pack2(a.x, a.y); v.y = pack2(a.z, a.w);
  v.z = pack2(b.x, b.y); v.w = pack2(b.z, b.w);
  reinterpret_cast<uint4*>(dst)[i] = v;
}

// --------------------------------------------------------------------------
// k1: xz = x @ Wi^T + bi  (bf16 MFMA, fp32 acc). A=XB (8192x1024),
// B=WIB (4096x1024, B^T layout). Grid (4096/128, 8192/128) = (32,64).
// Epilogue: cols < DI -> XIN bf16; cols >= DI -> ZG = silu bf16.
// --------------------------------------------------------------------------
__global__ __launch_bounds__(256)
void k1(const bf16* __restrict__ A, const bf16* __restrict__ W,
        const float* __restrict__ bi,
        bf16* __restrict__ XIN, bf16* __restrict__ ZG)
{
  __shared__ bf16 Al[128 * 32];
  __shared__ bf16 Bl[128 * 32];
  const int tid  = threadIdx.x;
  const int bm   = blockIdx.y * 128;
  const int bn   = blockIdx.x * 128;
  const int lane = tid & 63, wid = tid >> 6;
  const int wr = wid >> 1, wc = wid & 1;
  const int fr = lane & 15;
  const int kg = (lane >> 4) * 8;
  const int ldr = tid >> 2, ldc = (tid & 3) * 8;
  constexpr int K = DM;

  const bf16* ga = A + (size_t)(bm + ldr) * K + ldc;
  const bf16* gb = W + (size_t)(bn + ldr) * K + ldc;

  f32x4 acc[4][4];
#pragma unroll
  for (int i = 0; i < 4; ++i)
#pragma unroll
    for (int j = 0; j < 4; ++j) acc[i][j] = (f32x4){0.f, 0.f, 0.f, 0.f};

  for (int k0 = 0; k0 < K; k0 += 32) {
    GLOAD_LDS16(ga + k0,          &Al[tid * 8]);
    GLOAD_LDS16(ga + k0 + 64 * K, &Al[2048 + tid * 8]);
    GLOAD_LDS16(gb + k0,          &Bl[tid * 8]);
    GLOAD_LDS16(gb + k0 + 64 * K, &Bl[2048 + tid * 8]);
    asm volatile("s_waitcnt vmcnt(0)" ::: "memory");
    __syncthreads();
    bf16x8 af[4], bfr[4];
#pragma unroll
    for (int i = 0; i < 4; ++i)
      af[i]  = *(const bf16x8*)&Al[(wr * 64 + i * 16 + fr) * 32 + kg];
#pragma unroll
    for (int j = 0; j < 4; ++j)
      bfr[j] = *(const bf16x8*)&Bl[(wc * 64 + j * 16 + fr) * 32 + kg];
#pragma unroll
    for (int i = 0; i < 4; ++i)
#pragma unroll
      for (int j = 0; j < 4; ++j)
        acc[i][j] = __builtin_amdgcn_mfma_f32_16x16x32_bf16(
            af[i], bfr[j], acc[i][j], 0, 0, 0);
    __syncthreads();
  }

  const int r0 = (lane >> 4) * 4;
#pragma unroll
  for (int j = 0; j < 4; ++j) {
    const int col = bn + wc * 64 + j * 16 + fr;
    const float bv = bi[col];
    const bool isx = (col < DI);           // wave-uniform (64-aligned split)
#pragma unroll
    for (int i = 0; i < 4; ++i) {
      const int rowb = bm + wr * 64 + i * 16 + r0;
#pragma unroll
      for (int r = 0; r < 4; ++r) {
        const float v = acc[i][j][r] + bv;
        if (isx) XIN[(size_t)(rowb + r) * DI + col]        = f2b(v);
        else     ZG [(size_t)(rowb + r) * DI + (col - DI)] = f2b(silu_f(v));
      }
    }
  }
}

// --------------------------------------------------------------------------
// kscan: fused conv+dt+scan+gate, full T per (batch, d-block).
// Grid (DI/16, Bdim), 256 thr = 16d x 16n. h in registers all T.
// dt/u transposed+padded; serial loop float4-reads; DPP reduction.
// --------------------------------------------------------------------------
__global__ __launch_bounds__(256)
void kscan(const bf16* __restrict__ XIN, bf16* __restrict__ ZG,
           const float* __restrict__ cw, const float* __restrict__ cb,
           const float* __restrict__ Wdt, const float* __restrict__ bdt,
           const float* __restrict__ A_log, const float* __restrict__ Bm,
           const float* __restrict__ Cm)
{
  __shared__ float Wl[16][33];
  __shared__ float x32[64][33];
  __shared__ float xc[67][17];
  __shared__ float dts[16][68];   // [dl][tl], 68 = pad for bank spread
  __shared__ float us [16][68];
  __shared__ float ys [16][68];

  const int tid = threadIdx.x;
  const int n  = tid & 15;
  const int dl = tid >> 4;
  const int d0 = blockIdx.x * 16;
  const int d  = d0 + dl;
  const size_t rbase = (size_t)blockIdx.y * Tdim;

  const float Af = -__expf(A_log[(size_t)d * DS + n]);
  const float Bf = Bm[(size_t)d * DS + n];
  const float Cf = Cm[(size_t)d * DS + n];
  const float w0 = cw[d * DC + 0], w1 = cw[d * DC + 1];
  const float w2 = cw[d * DC + 2], w3 = cw[d * DC + 3];
  const float c0 = cb[d];
  const float bdtv = bdt[d];

  for (int e = tid; e < 16 * DTR; e += 256)
    Wl[e >> 5][e & 31] = Wdt[(size_t)(d0 + (e >> 5)) * DTR + (e & 31)];

  float h = 0.0f;

  for (int t0 = 0; t0 < Tdim; t0 += 64) {
    __syncthreads();
    for (int e = tid; e < 64 * 32; e += 256) {
      const int tl = e >> 5, r = e & 31;
      x32[tl][r] = b2f(XIN[(rbase + t0 + tl) * DI + r]);
    }
    for (int e = tid; e < 67 * 16; e += 256) {
      const int i = e >> 4, dd = e & 15;
      const int rr = t0 + i - 3;
      xc[i][dd] = (rr < 0) ? 0.0f : b2f(XIN[(rbase + rr) * DI + d0 + dd]);
    }
    __syncthreads();

#pragma unroll
    for (int q = 0; q < 4; ++q) {
      const int tl = n + 16 * q;
      const float cv = c0 + w0 * xc[tl][dl] + w1 * xc[tl + 1][dl]
                          + w2 * xc[tl + 2][dl] + w3 * xc[tl + 3][dl];
      us[dl][tl] = silu_f(cv);
      float a = bdtv;
#pragma unroll
      for (int r = 0; r < DTR; ++r) a += x32[tl][r] * Wl[dl][r];
      dts[dl][tl] = softplus_f(a);
    }
    __syncthreads();

#pragma unroll 4
    for (int tq = 0; tq < 16; ++tq) {
      const float4 dv = *(const float4*)&dts[dl][4 * tq];
      const float4 uv = *(const float4*)&us [dl][4 * tq];
#define SCAN_STEP(DT, UU, TL)                                                 \
      {                                                                       \
        const float dtv = (DT);                                               \
        h = h * __expf(dtv * Af) + (dtv * Bf) * (UU);                         \
        float y = h * Cf;                                                     \
        y += __int_as_float(__builtin_amdgcn_update_dpp(                      \
                 0, __float_as_int(y), 0x111, 0xf, 0xf, true));               \
        y += __int_as_float(__builtin_amdgcn_update_dpp(                      \
                 0, __float_as_int(y), 0x112, 0xf, 0xf, true));               \
        y += __int_as_float(__builtin_amdgcn_update_dpp(                      \
                 0, __float_as_int(y), 0x114, 0xf, 0xf, true));               \
        y += __int_as_float(__builtin_amdgcn_update_dpp(                      \
                 0, __float_as_int(y), 0x118, 0xf, 0xf, true));               \
        if (n == 15) ys[dl][TL] = y;                                          \
      }
      SCAN_STEP(dv.x, uv.x, 4 * tq + 0);
      SCAN_STEP(dv.y, uv.y, 4 * tq + 1);
      SCAN_STEP(dv.z, uv.z, 4 * tq + 2);
      SCAN_STEP(dv.w, uv.w, 4 * tq + 3);
#undef SCAN_STEP
    }
    __syncthreads();

    for (int e = tid; e < 64 * 16; e += 256) {
      const int tl = e >> 4, dd = e & 15;
      const size_t gi = (rbase + t0 + tl) * DI + d0 + dd;
      ZG[gi] = f2b(ys[dd][tl] * b2f(ZG[gi]));
    }
  }
}

// --------------------------------------------------------------------------
// k2: out = G @ Wo^T + bo + meanDv*x  (bf16 MFMA, fp32 acc, pure store).
// A=ZG (8192x2048), B=WOB (1024x2048). Grid (1024/128, 8192/128) = (8,64).
// --------------------------------------------------------------------------
__global__ __launch_bounds__(256)
void k2(const bf16* __restrict__ G, const bf16* __restrict__ W,
        const float* __restrict__ x, const float* __restrict__ bo,
        const float* __restrict__ meanp, float* __restrict__ out)
{
  __shared__ bf16 Al[128 * 32];
  __shared__ bf16 Bl[128 * 32];
  const int tid  = threadIdx.x;
  const int bm   = blockIdx.y * 128;
  const int bn   = blockIdx.x * 128;
  const int lane = tid & 63, wid = tid >> 6;
  const int wr = wid >> 1, wc = wid & 1;
  const int fr = lane & 15;
  const int kg = (lane >> 4) * 8;
  const int ldr = tid >> 2, ldc = (tid & 3) * 8;
  constexpr int K = DI;

  const bf16* ga = G + (size_t)(bm + ldr) * K + ldc;
  const bf16* gb = W + (size_t)(bn + ldr) * K + ldc;
  const float mv = *meanp;

  f32x4 acc[4][4];
#pragma unroll
  for (int i = 0; i < 4; ++i)
#pragma unroll
    for (int j = 0; j < 4; ++j) acc[i][j] = (f32x4){0.f, 0.f, 0.f, 0.f};

  for (int k0 = 0; k0 < K; k0 += 32) {
    GLOAD_LDS16(ga + k0,          &Al[tid * 8]);
    GLOAD_LDS16(ga + k0 + 64 * K, &Al[2048 + tid * 8]);
    GLOAD_LDS16(gb + k0,          &Bl[tid * 8]);
    GLOAD_LDS16(gb + k0 + 64 * K, &Bl[2048 + tid * 8]);
    asm volatile("s_waitcnt vmcnt(0)" ::: "memory");
    __syncthreads();
    bf16x8 af[4], bfr[4];
#pragma unroll
    for (int i = 0; i < 4; ++i)
      af[i]  = *(const bf16x8*)&Al[(wr * 64 + i * 16 + fr) * 32 + kg];
#pragma unroll
    for (int j = 0; j < 4; ++j)
      bfr[j] = *(const bf16x8*)&Bl[(wc * 64 + j * 16 + fr) * 32 + kg];
#pragma unroll
    for (int i = 0; i < 4; ++i)
#pragma unroll
      for (int j = 0; j < 4; ++j)
        acc[i][j] = __builtin_amdgcn_mfma_f32_16x16x32_bf16(
            af[i], bfr[j], acc[i][j], 0, 0, 0);
    __syncthreads();
  }

  const int r0 = (lane >> 4) * 4;
#pragma unroll
  for (int j = 0; j < 4; ++j) {
    const int col = bn + wc * 64 + j * 16 + fr;
    const float bv = bo[col];
#pragma unroll
    for (int i = 0; i < 4; ++i) {
      const int rowb = bm + wr * 64 + i * 16 + r0;
#pragma unroll
      for (int r = 0; r < 4; ++r) {
        const size_t oi = (size_t)(rowb + r) * DM + col;
        out[oi] = acc[i][j][r] + bv + mv * x[oi];
      }
    }
  }
}

// --------------------------------------------------------------------------
extern "C" void kernel_launch(void* const* d_in, const int* in_sizes, int n_in,
                              void* d_out, int out_size, void* d_ws, size_t ws_size,
                              hipStream_t stream)
{
  const float* x    = (const float*)d_in[0];
  const float* Wi   = (const float*)d_in[1];
  const float* bi   = (const float*)d_in[2];
  const float* cw   = (const float*)d_in[3];
  const float* cb   = (const float*)d_in[4];
  const float* Wdt  = (const float*)d_in[5];
  const float* bdt  = (const float*)d_in[6];
  const float* Alog = (const float*)d_in[7];
  const float* Bm   = (const float*)d_in[8];
  const float* Cm   = (const float*)d_in[9];
  const float* Dv   = (const float*)d_in[10];
  const float* Wo   = (const float*)d_in[11];
  const float* bo   = (const float*)d_in[12];
  float* out = (float*)d_out;

  char* ws = (char*)d_ws;
  float* MEANP = (float*)(ws);
  bf16*  XB    = (bf16*)(ws + 256);
  bf16*  WIB   = (bf16*)(ws + 16777472);
  bf16*  WOB   = (bf16*)(ws + 25166080);
  bf16*  XIN   = (bf16*)(ws + 29360384);
  bf16*  ZG    = (bf16*)(ws + 62914816);
  // total ws use: 96,469,248 B

  kmean<<<1, 256, 0, stream>>>(Dv, MEANP);
  kcvt<<<Mrows * DM / 8 / 256, 256, 0, stream>>>(x,  XB,  Mrows * DM / 8);
  kcvt<<<2 * DI * DM / 8 / 256, 256, 0, stream>>>(Wi, WIB, 2 * DI * DM / 8);
  kcvt<<<DM * DI / 8 / 256, 256, 0, stream>>>(Wo, WOB, DM * DI / 8);

  k1<<<dim3(2 * DI / 128, Mrows / 128), 256, 0, stream>>>(XB, WIB, bi, XIN, ZG);
  kscan<<<dim3(DI / 16, Bdim), 256, 0, stream>>>(
      XIN, ZG, cw, cb, Wdt, bdt, Alog, Bm, Cm);
  k2<<<dim3(DM / 128, Mrows / 128), 256, 0, stream>>>(ZG, WOB, x, bo, MEANP, out);
}